// Round 1
// baseline (6873.189 us; speedup 1.0000x reference)
//
#include <hip/hip_runtime.h>

#define TT 128
#define NN 512
#define DH 64
#define EE 8192

__device__ __forceinline__ float silu_f(float x) {
    return x / (1.0f + __expf(-x));
}

// h[tt,n,d] = t[tt]*enc_w[0,d] + enc_w[1+n,d] + enc_b[d]
__global__ __launch_bounds__(256) void encode_kernel(
    const float* __restrict__ t, const float* __restrict__ enc_w,
    const float* __restrict__ enc_b, float* __restrict__ h) {
    int idx = blockIdx.x * 256 + threadIdx.x;   // over TT*NN*DH
    int d  = idx & 63;
    int n  = (idx >> 6) & (NN - 1);
    int tt = idx >> 15;
    h[idx] = t[tt] * enc_w[d] + enc_w[(1 + n) * DH + d] + enc_b[d];
}

// One wave per (tt, e). Lane d owns output channel d.
__global__ __launch_bounds__(256) void msg_kernel(
    const float* __restrict__ h, const int* __restrict__ ei,
    const float* __restrict__ w1, const float* __restrict__ b1,
    const float* __restrict__ w2, const float* __restrict__ b2,
    float* __restrict__ agg) {
    int lane = threadIdx.x & 63;
    int wid  = blockIdx.x * 4 + (threadIdx.x >> 6);  // tt*EE + e
    int tt   = wid >> 13;                             // EE = 8192
    int e    = wid & (EE - 1);
    int src  = ei[e];
    int dst  = ei[EE + e];
    const float* hs_row = h + ((size_t)(tt * NN + src) << 6);
    const float* hd_row = h + ((size_t)(tt * NN + dst) << 6);
    float hs = hs_row[lane];
    float hd = hd_row[lane];

    float acc = b1[lane];
    #pragma unroll 16
    for (int k = 0; k < 64; ++k) {
        acc += __shfl(hs, k) * w1[k * DH + lane];
        acc += __shfl(hd, k) * w1[(DH + k) * DH + lane];
    }
    float hidv = silu_f(acc);

    float m = b2[lane];
    #pragma unroll 16
    for (int k = 0; k < 64; ++k) {
        m += __shfl(hidv, k) * w2[k * DH + lane];
    }
    atomicAdd(agg + (((size_t)(tt * NN + dst)) << 6) + lane, m);
}

// One wave per (tt, n) row. u = [h_row, agg_row]; h += silu(u@W1+b1)@W2+b2
__global__ __launch_bounds__(256) void upd_kernel(
    float* __restrict__ h, const float* __restrict__ agg,
    const float* __restrict__ w1, const float* __restrict__ b1,
    const float* __restrict__ w2, const float* __restrict__ b2) {
    int lane = threadIdx.x & 63;
    int row  = blockIdx.x * 4 + (threadIdx.x >> 6);  // tt*NN + n
    float* hrow = h + ((size_t)row << 6);
    float hv = hrow[lane];
    float av = agg[((size_t)row << 6) + lane];

    float acc = b1[lane];
    #pragma unroll 16
    for (int k = 0; k < 64; ++k) {
        acc += __shfl(hv, k) * w1[k * DH + lane];
        acc += __shfl(av, k) * w1[(DH + k) * DH + lane];
    }
    float hidv = silu_f(acc);

    float u = b2[lane];
    #pragma unroll 16
    for (int k = 0; k < 64; ++k) {
        u += __shfl(hidv, k) * w2[k * DH + lane];
    }
    hrow[lane] = hv + u;
}

// out[tt,n] = sum_d h[tt,n,d]*ro_w[d] + ro_b
__global__ __launch_bounds__(256) void readout_kernel(
    const float* __restrict__ h, const float* __restrict__ ro_w,
    const float* __restrict__ ro_b, float* __restrict__ out) {
    int lane = threadIdx.x & 63;
    int row  = blockIdx.x * 4 + (threadIdx.x >> 6);  // tt*NN + n
    float v = h[((size_t)row << 6) + lane] * ro_w[lane];
    #pragma unroll
    for (int off = 32; off > 0; off >>= 1) v += __shfl_xor(v, off);
    if (lane == 0) out[row] = v + ro_b[0];
}

extern "C" void kernel_launch(void* const* d_in, const int* in_sizes, int n_in,
                              void* d_out, int out_size, void* d_ws, size_t ws_size,
                              hipStream_t stream) {
    const float* t      = (const float*)d_in[0];
    const int*   ei     = (const int*)d_in[1];   // [2, E] int32
    const float* enc_w  = (const float*)d_in[2];
    const float* enc_b  = (const float*)d_in[3];
    const float* msg1_w = (const float*)d_in[4];
    const float* msg1_b = (const float*)d_in[5];
    const float* msg2_w = (const float*)d_in[6];
    const float* msg2_b = (const float*)d_in[7];
    const float* upd1_w = (const float*)d_in[8];
    const float* upd1_b = (const float*)d_in[9];
    const float* upd2_w = (const float*)d_in[10];
    const float* upd2_b = (const float*)d_in[11];
    const float* ro_w   = (const float*)d_in[12];
    const float* ro_b   = (const float*)d_in[13];
    float* out = (float*)d_out;

    float* h   = (float*)d_ws;                       // [TT,NN,DH] f32 = 16 MB
    float* agg = h + (size_t)TT * NN * DH;           // [TT,NN,DH] f32 = 16 MB

    encode_kernel<<<TT * NN * DH / 256, 256, 0, stream>>>(t, enc_w, enc_b, h);

    for (int l = 0; l < 3; ++l) {
        hipMemsetAsync(agg, 0, (size_t)TT * NN * DH * sizeof(float), stream);
        msg_kernel<<<TT * EE / 4, 256, 0, stream>>>(
            h, ei,
            msg1_w + (size_t)l * 2 * DH * DH, msg1_b + l * DH,
            msg2_w + (size_t)l * DH * DH,     msg2_b + l * DH, agg);
        upd_kernel<<<TT * NN / 4, 256, 0, stream>>>(
            h, agg,
            upd1_w + (size_t)l * 2 * DH * DH, upd1_b + l * DH,
            upd2_w + (size_t)l * DH * DH,     upd2_b + l * DH);
    }

    readout_kernel<<<TT * NN / 4, 256, 0, stream>>>(h, ro_w, ro_b, out);
}

// Round 2
// 1038.967 us; speedup vs baseline: 6.6154x; 6.6154x over previous
//
#include <hip/hip_runtime.h>

#define TT 128
#define NN 512
#define DH 64
#define EE 8192

__device__ __forceinline__ float silu_f(float x) {
    return x / (1.0f + __expf(-x));
}

// ---- CSR build (per launch; edges fixed across layers) ----
__global__ __launch_bounds__(256) void hist_kernel(const int* __restrict__ ei,
                                                   int* __restrict__ counts) {
    int e = blockIdx.x * 256 + threadIdx.x;
    atomicAdd(&counts[ei[EE + e]], 1);
}

__global__ __launch_bounds__(512) void scan_kernel(const int* __restrict__ counts,
                                                   int* __restrict__ offsets,
                                                   int* __restrict__ cursor) {
    __shared__ int tmp[NN];
    int i = threadIdx.x;
    int c = counts[i];
    tmp[i] = c;
    __syncthreads();
    for (int off = 1; off < NN; off <<= 1) {
        int v = (i >= off) ? tmp[i - off] : 0;
        __syncthreads();
        tmp[i] += v;
        __syncthreads();
    }
    offsets[i + 1] = tmp[i];
    if (i == 0) offsets[0] = 0;
    cursor[i] = tmp[i] - c;   // exclusive prefix
}

__global__ __launch_bounds__(256) void scatter_kernel(const int* __restrict__ ei,
                                                      int* __restrict__ cursor,
                                                      int* __restrict__ ssrc) {
    int e = blockIdx.x * 256 + threadIdx.x;
    int dst = ei[EE + e];
    int pos = atomicAdd(&cursor[dst], 1);
    ssrc[pos] = ei[e];
}

// ---- encode + layer-0 src-projection ----
// h[tt,n,d] = t[tt]*enc_w[0,d] + enc_w[1+n,d] + enc_b[d];  Hs = h @ W1_top
__global__ __launch_bounds__(256) void encode_proj_kernel(
    const float* __restrict__ t, const float* __restrict__ enc_w,
    const float* __restrict__ enc_b, const float* __restrict__ w1,
    float* __restrict__ h, float* __restrict__ hs) {
    int lane = threadIdx.x & 63;
    int row  = blockIdx.x * 4 + (threadIdx.x >> 6);  // tt*NN + n
    int n    = row & (NN - 1);
    int tt   = row >> 9;
    float hv = t[tt] * enc_w[lane] + enc_w[(1 + n) * DH + lane] + enc_b[lane];
    h[(size_t)row * DH + lane] = hv;
    float a = 0.f;
    #pragma unroll 16
    for (int k = 0; k < DH; ++k) a += __shfl(hv, k) * w1[k * DH + lane];
    hs[(size_t)row * DH + lane] = a;
}

// ---- edge aggregation, one wave per (tt, dst-node), no atomics ----
// aggpre[tt,n,:] = sum_{e: dst(e)=n} silu(Hs[tt,src(e),:] + h[tt,n,:]@W1_bot + b1)
__global__ __launch_bounds__(256) void agg_kernel(
    const float* __restrict__ h, const float* __restrict__ hs,
    const float* __restrict__ w1, const float* __restrict__ b1,
    const int* __restrict__ offsets, const int* __restrict__ ssrc,
    float* __restrict__ aggpre) {
    int lane = threadIdx.x & 63;
    int n    = blockIdx.x * 4 + (threadIdx.x >> 6);
    int tt   = blockIdx.y;
    int row  = tt * NN + n;
    float hv = h[(size_t)row * DH + lane];
    float hdp = b1[lane];
    #pragma unroll 16
    for (int k = 0; k < DH; ++k) hdp += __shfl(hv, k) * w1[(DH + k) * DH + lane];
    int beg = offsets[n], end = offsets[n + 1];
    const float* hs_t = hs + ((size_t)tt * NN) * DH;
    float acc = 0.f;
    for (int base = beg; base < end; base += 64) {
        int m = end - base; if (m > 64) m = 64;
        int my = (lane < m) ? ssrc[base + lane] : 0;
        for (int j = 0; j < m; ++j) {
            int s = __shfl(my, j);
            acc += silu_f(hs_t[(size_t)s * DH + lane] + hdp);
        }
    }
    aggpre[(size_t)row * DH + lane] = acc;
}

// ---- update MLP (+ next-layer src-proj OR fused readout) ----
// agg = aggpre@W2 + deg*b2 ; h_new = h + silu([h,agg]@U1+ub1)@U2+ub2
__global__ __launch_bounds__(256) void upd_kernel(
    float* __restrict__ h, const float* __restrict__ aggpre,
    const int* __restrict__ counts,
    const float* __restrict__ w2, const float* __restrict__ b2,
    const float* __restrict__ u1, const float* __restrict__ ub1,
    const float* __restrict__ u2, const float* __restrict__ ub2,
    const float* __restrict__ w1n, float* __restrict__ hs,
    const float* __restrict__ ro_w, const float* __restrict__ ro_b,
    float* __restrict__ out, int last) {
    int lane = threadIdx.x & 63;
    int row  = blockIdx.x * 4 + (threadIdx.x >> 6);  // tt*NN + n
    int n    = row & (NN - 1);
    float hv = h[(size_t)row * DH + lane];
    float ap = aggpre[(size_t)row * DH + lane];
    float deg = (float)counts[n];

    float ag = deg * b2[lane];
    #pragma unroll 16
    for (int k = 0; k < DH; ++k) ag += __shfl(ap, k) * w2[k * DH + lane];

    float acc = ub1[lane];
    #pragma unroll 8
    for (int k = 0; k < DH; ++k) {
        acc += __shfl(hv, k) * u1[k * DH + lane];
        acc += __shfl(ag, k) * u1[(DH + k) * DH + lane];
    }
    float hid = silu_f(acc);

    float u = ub2[lane];
    #pragma unroll 16
    for (int k = 0; k < DH; ++k) u += __shfl(hid, k) * u2[k * DH + lane];
    float hnew = hv + u;

    if (!last) {
        h[(size_t)row * DH + lane] = hnew;
        float a = 0.f;
        #pragma unroll 16
        for (int k = 0; k < DH; ++k) a += __shfl(hnew, k) * w1n[k * DH + lane];
        hs[(size_t)row * DH + lane] = a;
    } else {
        float v = hnew * ro_w[lane];
        #pragma unroll
        for (int off = 32; off > 0; off >>= 1) v += __shfl_xor(v, off);
        if (lane == 0) out[row] = v + ro_b[0];
    }
}

extern "C" void kernel_launch(void* const* d_in, const int* in_sizes, int n_in,
                              void* d_out, int out_size, void* d_ws, size_t ws_size,
                              hipStream_t stream) {
    const float* t      = (const float*)d_in[0];
    const int*   ei     = (const int*)d_in[1];
    const float* enc_w  = (const float*)d_in[2];
    const float* enc_b  = (const float*)d_in[3];
    const float* msg1_w = (const float*)d_in[4];
    const float* msg1_b = (const float*)d_in[5];
    const float* msg2_w = (const float*)d_in[6];
    const float* msg2_b = (const float*)d_in[7];
    const float* upd1_w = (const float*)d_in[8];
    const float* upd1_b = (const float*)d_in[9];
    const float* upd2_w = (const float*)d_in[10];
    const float* upd2_b = (const float*)d_in[11];
    const float* ro_w   = (const float*)d_in[12];
    const float* ro_b   = (const float*)d_in[13];
    float* out = (float*)d_out;

    const size_t HN = (size_t)TT * NN * DH;          // 4 M floats = 16 MB
    float* h      = (float*)d_ws;
    float* hs     = h + HN;
    float* aggpre = hs + HN;
    int*   counts  = (int*)(aggpre + HN);
    int*   offsets = counts + NN;                     // NN+1
    int*   cursor  = offsets + NN + 1;
    int*   ssrc    = cursor + NN;

    hipMemsetAsync(counts, 0, NN * sizeof(int), stream);
    hist_kernel<<<EE / 256, 256, 0, stream>>>(ei, counts);
    scan_kernel<<<1, NN, 0, stream>>>(counts, offsets, cursor);
    scatter_kernel<<<EE / 256, 256, 0, stream>>>(ei, cursor, ssrc);

    encode_proj_kernel<<<TT * NN / 4, 256, 0, stream>>>(t, enc_w, enc_b,
                                                        msg1_w, h, hs);

    for (int l = 0; l < 3; ++l) {
        agg_kernel<<<dim3(NN / 4, TT), 256, 0, stream>>>(
            h, hs,
            msg1_w + (size_t)l * 2 * DH * DH, msg1_b + (size_t)l * DH,
            offsets, ssrc, aggpre);
        int last = (l == 2);
        upd_kernel<<<TT * NN / 4, 256, 0, stream>>>(
            h, aggpre, counts,
            msg2_w + (size_t)l * DH * DH, msg2_b + (size_t)l * DH,
            upd1_w + (size_t)l * 2 * DH * DH, upd1_b + (size_t)l * DH,
            upd2_w + (size_t)l * DH * DH, upd2_b + (size_t)l * DH,
            last ? msg1_w : msg1_w + (size_t)(l + 1) * 2 * DH * DH,
            hs, ro_w, ro_b, out, last);
    }
}

// Round 4
// 461.350 us; speedup vs baseline: 14.8980x; 2.2520x over previous
//
#include <hip/hip_runtime.h>

#define TT 128
#define TH 64            // t-rows staged per pass (2 passes)
#define NN 512
#define DH 64
#define EE 8192
#define LOB (18 * 8 * 64)   // uint4 offset of lo-weight fragments

typedef __bf16 bf16x8 __attribute__((ext_vector_type(8)));
typedef float f32x4 __attribute__((ext_vector_type(4)));

struct US8 { unsigned short u[8]; };
struct Frag { bf16x8 hi, lo; };

static __device__ __forceinline__ unsigned short f2bf(float x) {
    union { float f; unsigned u; } c; c.f = x;
    unsigned r = (c.u + 0x7FFFu + ((c.u >> 16) & 1u)) >> 16;   // RNE
    return (unsigned short)r;
}
static __device__ __forceinline__ float bf2f(unsigned short b) {
    union { unsigned u; float f; } c; c.u = ((unsigned)b) << 16;
    return c.f;
}
static __device__ __forceinline__ float silu_f(float x) {
    return x / (1.0f + __expf(-x));
}
static __device__ __forceinline__ Frag split8(const float* v) {
    US8 h8, l8;
    #pragma unroll
    for (int i = 0; i < 8; ++i) {
        unsigned short hu = f2bf(v[i]);
        h8.u[i] = hu;
        l8.u[i] = f2bf(v[i] - bf2f(hu));
    }
    Frag f;
    f.hi = __builtin_bit_cast(bf16x8, h8);
    f.lo = __builtin_bit_cast(bf16x8, l8);
    return f;
}
static __device__ __forceinline__ f32x4 mmac(bf16x8 a, uint4 bw, f32x4 c) {
    return __builtin_amdgcn_mfma_f32_16x16x32_bf16(
        a, __builtin_bit_cast(bf16x8, bw), c, 0, 0, 0);
}
// 3-term split-precision MFMA: a@W with ~fp32 accuracy
static __device__ __forceinline__ f32x4 mm3(Frag a, uint4 wh, uint4 wl, f32x4 c) {
    c = mmac(a.hi, wh, c);
    c = mmac(a.lo, wh, c);
    c = mmac(a.hi, wl, c);
    return c;
}

// ---- CSR build ----
__global__ __launch_bounds__(256) void hist_kernel(const int* __restrict__ ei,
                                                   int* __restrict__ counts) {
    int e = blockIdx.x * 256 + threadIdx.x;
    atomicAdd(&counts[ei[EE + e]], 1);
}

__global__ __launch_bounds__(512) void scan_kernel(const int* __restrict__ counts,
                                                   int* __restrict__ offsets,
                                                   int* __restrict__ cursor) {
    __shared__ int tmp[NN];
    int i = threadIdx.x;
    int c = counts[i];
    tmp[i] = c;
    __syncthreads();
    for (int off = 1; off < NN; off <<= 1) {
        int v = (i >= off) ? tmp[i - off] : 0;
        __syncthreads();
        tmp[i] += v;
        __syncthreads();
    }
    offsets[i + 1] = tmp[i];
    if (i == 0) offsets[0] = 0;
    cursor[i] = tmp[i] - c;
}

__global__ __launch_bounds__(256) void scatter_kernel(const int* __restrict__ ei,
                                                      int* __restrict__ cursor,
                                                      int* __restrict__ ssrc) {
    int e = blockIdx.x * 256 + threadIdx.x;
    int dst = ei[EE + e];
    int pos = atomicAdd(&cursor[dst], 1);
    ssrc[pos] = ei[e];
}

// ---- weight prepack: 18 blocks of 64x64 -> hi/lo bf16 B-fragments ----
__global__ __launch_bounds__(64) void prepack_kernel(
    const float* __restrict__ msg1_w, const float* __restrict__ msg2_w,
    const float* __restrict__ upd1_w, const float* __restrict__ upd2_w,
    uint4* __restrict__ pack) {
    int b = blockIdx.x;            // 0..17
    int l = b / 6, bi = b % 6;
    const float* W;
    if (bi == 0)      W = msg1_w + (size_t)l * 128 * 64;
    else if (bi == 1) W = msg1_w + (size_t)l * 128 * 64 + 64 * 64;
    else if (bi == 2) W = msg2_w + (size_t)l * 64 * 64;
    else if (bi == 3) W = upd1_w + (size_t)l * 128 * 64;
    else if (bi == 4) W = upd1_w + (size_t)l * 128 * 64 + 64 * 64;
    else              W = upd2_w + (size_t)l * 64 * 64;
    int lane = threadIdx.x;
    for (int nt = 0; nt < 4; ++nt)
        for (int kc = 0; kc < 2; ++kc) {
            US8 oh, ol;
            #pragma unroll
            for (int i = 0; i < 8; ++i) {
                int k = kc * 32 + (lane >> 4) * 8 + i;
                int col = nt * 16 + (lane & 15);
                float w = W[k * 64 + col];
                unsigned short hu = f2bf(w);
                oh.u[i] = hu;
                ol.u[i] = f2bf(w - bf2f(hu));
            }
            size_t fi = ((size_t)b * 8 + nt * 2 + kc) * 64 + lane;
            pack[fi]       = __builtin_bit_cast(uint4, oh);
            pack[LOB * 64 + fi] = __builtin_bit_cast(uint4, ol);
        }
}

// ---- encode + layer-0 projections (split MFMA). Wave = 16 rows. ----
__global__ __launch_bounds__(256) void encode_mfma_kernel(
    const float* __restrict__ t, const float* __restrict__ enc_w,
    const float* __restrict__ enc_b, const float* __restrict__ b1,
    const uint4* __restrict__ pack,
    float* __restrict__ h, float* __restrict__ hs, float* __restrict__ hd) {
    int lane = threadIdx.x & 63;
    int rowbase = blockIdx.x * 64 + (threadIdx.x >> 6) * 16;
    int arow = lane & 15, kgrp = lane >> 4, k0 = kgrp * 8;
    int row = rowbase + arow;
    int tt = row >> 9, n = row & (NN - 1);
    float tv = t[tt];

    float hv[16];
    #pragma unroll
    for (int kc = 0; kc < 2; ++kc) {
        #pragma unroll
        for (int i = 0; i < 8; ++i) {
            int k = kc * 32 + k0 + i;
            hv[kc * 8 + i] = tv * enc_w[k] + enc_w[(1 + n) * DH + k] + enc_b[k];
        }
        *(float4*)(h + (size_t)row * DH + kc * 32 + k0) =
            make_float4(hv[kc * 8], hv[kc * 8 + 1], hv[kc * 8 + 2], hv[kc * 8 + 3]);
        *(float4*)(h + (size_t)row * DH + kc * 32 + k0 + 4) =
            make_float4(hv[kc * 8 + 4], hv[kc * 8 + 5], hv[kc * 8 + 6], hv[kc * 8 + 7]);
    }
    Frag a0 = split8(&hv[0]), a1 = split8(&hv[8]);

    const uint4* PWtH = pack;                 // layer0 W1top hi
    const uint4* PWbH = pack + 8 * 64;        // layer0 W1bot hi
    const uint4* PWtL = PWtH + LOB * 64;
    const uint4* PWbL = PWbH + LOB * 64;
    #pragma unroll
    for (int nt = 0; nt < 4; ++nt) {
        f32x4 s; f32x4 d;
        float b1v = b1[nt * 16 + (lane & 15)];
        #pragma unroll
        for (int r = 0; r < 4; ++r) { s[r] = 0.f; d[r] = b1v; }
        s = mm3(a0, PWtH[(nt * 2 + 0) * 64 + lane], PWtL[(nt * 2 + 0) * 64 + lane], s);
        s = mm3(a1, PWtH[(nt * 2 + 1) * 64 + lane], PWtL[(nt * 2 + 1) * 64 + lane], s);
        d = mm3(a0, PWbH[(nt * 2 + 0) * 64 + lane], PWbL[(nt * 2 + 0) * 64 + lane], d);
        d = mm3(a1, PWbH[(nt * 2 + 1) * 64 + lane], PWbL[(nt * 2 + 1) * 64 + lane], d);
        #pragma unroll
        for (int r = 0; r < 4; ++r) {
            int rr = rowbase + kgrp * 4 + r;
            hs[(size_t)rr * DH + nt * 16 + (lane & 15)] = s[r];
            hd[(size_t)rr * DH + nt * 16 + (lane & 15)] = d[r];
        }
    }
}

// ---- edge aggregation: pure gather + silu + accumulate (fp32) ----
__global__ __launch_bounds__(256) void agg_kernel(
    const float* __restrict__ hs, const float* __restrict__ hd,
    const int* __restrict__ offsets, const int* __restrict__ ssrc,
    float* __restrict__ aggpre) {
    int lane = threadIdx.x & 63;
    int n = blockIdx.x * 4 + (threadIdx.x >> 6);
    int tt = blockIdx.y;
    size_t rowoff = ((size_t)tt * NN + n) * DH;
    float hdv = hd[rowoff + lane];
    int beg = offsets[n], end = offsets[n + 1];
    const float* hst = hs + (size_t)tt * NN * DH;
    float acc = 0.f;
    for (int base = beg; base < end; base += 64) {
        int m = end - base; if (m > 64) m = 64;
        int my = (lane < m) ? ssrc[base + lane] : 0;
        for (int j = 0; j < m; ++j) {
            int s = __shfl(my, j);
            acc += silu_f(hst[(size_t)s * DH + lane] + hdv);
        }
    }
    aggpre[rowoff + lane] = acc;
}

// ---- fused update MLP + (next-layer projections | readout), split MFMA ----
__global__ __launch_bounds__(256) void upd_mfma_kernel(
    float* __restrict__ h, const float* __restrict__ aggpre,
    const int* __restrict__ counts, const uint4* __restrict__ pack, int l,
    const float* __restrict__ b2, const float* __restrict__ ub1,
    const float* __restrict__ ub2, const float* __restrict__ b1n,
    float* __restrict__ hs, float* __restrict__ hd,
    const float* __restrict__ ro_w, const float* __restrict__ ro_b,
    float* __restrict__ out, int last) {
    __shared__ float tileA[4][16 * 68];
    __shared__ float tileB[4][16 * 68];
    int lane = threadIdx.x & 63;
    int w = threadIdx.x >> 6;
    int rowbase = blockIdx.x * 64 + w * 16;
    float* TA = tileA[w];
    float* TB = tileB[w];
    int arow = lane & 15, kgrp = lane >> 4, k0 = kgrp * 8;
    int hrow = rowbase + arow;

    float hf[16];
    *(float4*)&hf[0]  = *(const float4*)(h + (size_t)hrow * DH + k0);
    *(float4*)&hf[4]  = *(const float4*)(h + (size_t)hrow * DH + k0 + 4);
    *(float4*)&hf[8]  = *(const float4*)(h + (size_t)hrow * DH + 32 + k0);
    *(float4*)&hf[12] = *(const float4*)(h + (size_t)hrow * DH + 32 + k0 + 4);
    Frag ha0 = split8(&hf[0]), ha1 = split8(&hf[8]);

    float gf[16];
    *(float4*)&gf[0]  = *(const float4*)(aggpre + (size_t)hrow * DH + k0);
    *(float4*)&gf[4]  = *(const float4*)(aggpre + (size_t)hrow * DH + k0 + 4);
    *(float4*)&gf[8]  = *(const float4*)(aggpre + (size_t)hrow * DH + 32 + k0);
    *(float4*)&gf[12] = *(const float4*)(aggpre + (size_t)hrow * DH + 32 + k0 + 4);
    Frag ga0 = split8(&gf[0]), ga1 = split8(&gf[8]);

    // stage 1: agg = aggpre @ W2 + deg * b2
    const uint4* PW2H = pack + (size_t)(l * 6 + 2) * 8 * 64;
    const uint4* PW2L = PW2H + LOB * 64;
    float degv[4];
    #pragma unroll
    for (int r = 0; r < 4; ++r)
        degv[r] = (float)counts[(rowbase + kgrp * 4 + r) & (NN - 1)];
    #pragma unroll
    for (int nt = 0; nt < 4; ++nt) {
        float b2v = b2[nt * 16 + (lane & 15)];
        f32x4 a;
        #pragma unroll
        for (int r = 0; r < 4; ++r) a[r] = degv[r] * b2v;
        a = mm3(ga0, PW2H[(nt * 2 + 0) * 64 + lane], PW2L[(nt * 2 + 0) * 64 + lane], a);
        a = mm3(ga1, PW2H[(nt * 2 + 1) * 64 + lane], PW2L[(nt * 2 + 1) * 64 + lane], a);
        #pragma unroll
        for (int r = 0; r < 4; ++r)
            TA[(kgrp * 4 + r) * 68 + nt * 16 + (lane & 15)] = a[r];
    }
    float za[16];
    #pragma unroll
    for (int i = 0; i < 8; ++i) za[i] = TA[arow * 68 + k0 + i];
    #pragma unroll
    for (int i = 0; i < 8; ++i) za[8 + i] = TA[arow * 68 + 32 + k0 + i];
    Frag ka0 = split8(&za[0]), ka1 = split8(&za[8]);

    // stage 2: z = silu([h, agg] @ U1 + ub1)
    const uint4* PU1tH = pack + (size_t)(l * 6 + 3) * 8 * 64;
    const uint4* PU1bH = pack + (size_t)(l * 6 + 4) * 8 * 64;
    const uint4* PU1tL = PU1tH + LOB * 64;
    const uint4* PU1bL = PU1bH + LOB * 64;
    #pragma unroll
    for (int nt = 0; nt < 4; ++nt) {
        float bv = ub1[nt * 16 + (lane & 15)];
        f32x4 a;
        #pragma unroll
        for (int r = 0; r < 4; ++r) a[r] = bv;
        a = mm3(ha0, PU1tH[(nt * 2 + 0) * 64 + lane], PU1tL[(nt * 2 + 0) * 64 + lane], a);
        a = mm3(ha1, PU1tH[(nt * 2 + 1) * 64 + lane], PU1tL[(nt * 2 + 1) * 64 + lane], a);
        a = mm3(ka0, PU1bH[(nt * 2 + 0) * 64 + lane], PU1bL[(nt * 2 + 0) * 64 + lane], a);
        a = mm3(ka1, PU1bH[(nt * 2 + 1) * 64 + lane], PU1bL[(nt * 2 + 1) * 64 + lane], a);
        #pragma unroll
        for (int r = 0; r < 4; ++r)
            TB[(kgrp * 4 + r) * 68 + nt * 16 + (lane & 15)] = silu_f(a[r]);
    }
    float zb[16];
    #pragma unroll
    for (int i = 0; i < 8; ++i) zb[i] = TB[arow * 68 + k0 + i];
    #pragma unroll
    for (int i = 0; i < 8; ++i) zb[8 + i] = TB[arow * 68 + 32 + k0 + i];
    Frag kz0 = split8(&zb[0]), kz1 = split8(&zb[8]);

    // stage 3: hnew = h + z @ U2 + ub2
    const uint4* PU2H = pack + (size_t)(l * 6 + 5) * 8 * 64;
    const uint4* PU2L = PU2H + LOB * 64;
    #pragma unroll
    for (int nt = 0; nt < 4; ++nt) {
        float bv = ub2[nt * 16 + (lane & 15)];
        f32x4 a;
        #pragma unroll
        for (int r = 0; r < 4; ++r) a[r] = bv;
        a = mm3(kz0, PU2H[(nt * 2 + 0) * 64 + lane], PU2L[(nt * 2 + 0) * 64 + lane], a);
        a = mm3(kz1, PU2H[(nt * 2 + 1) * 64 + lane], PU2L[(nt * 2 + 1) * 64 + lane], a);
        #pragma unroll
        for (int r = 0; r < 4; ++r)
            TA[(kgrp * 4 + r) * 68 + nt * 16 + (lane & 15)] = a[r];
    }
    float hn[16];
    #pragma unroll
    for (int i = 0; i < 8; ++i) hn[i] = hf[i] + TA[arow * 68 + k0 + i];
    #pragma unroll
    for (int i = 0; i < 8; ++i) hn[8 + i] = hf[8 + i] + TA[arow * 68 + 32 + k0 + i];

    if (last) {
        float v = 0.f;
        #pragma unroll
        for (int i = 0; i < 8; ++i) v += hn[i] * ro_w[k0 + i];
        #pragma unroll
        for (int i = 0; i < 8; ++i) v += hn[8 + i] * ro_w[32 + k0 + i];
        v += __shfl_xor(v, 16);
        v += __shfl_xor(v, 32);
        if (lane < 16) out[rowbase + lane] = v + ro_b[0];
        return;
    }

    *(float4*)(h + (size_t)hrow * DH + k0) = make_float4(hn[0], hn[1], hn[2], hn[3]);
    *(float4*)(h + (size_t)hrow * DH + k0 + 4) = make_float4(hn[4], hn[5], hn[6], hn[7]);
    *(float4*)(h + (size_t)hrow * DH + 32 + k0) = make_float4(hn[8], hn[9], hn[10], hn[11]);
    *(float4*)(h + (size_t)hrow * DH + 32 + k0 + 4) = make_float4(hn[12], hn[13], hn[14], hn[15]);

    Frag na0 = split8(&hn[0]), na1 = split8(&hn[8]);
    const uint4* PWtH = pack + (size_t)((l + 1) * 6 + 0) * 8 * 64;
    const uint4* PWbH = pack + (size_t)((l + 1) * 6 + 1) * 8 * 64;
    const uint4* PWtL = PWtH + LOB * 64;
    const uint4* PWbL = PWbH + LOB * 64;
    #pragma unroll
    for (int nt = 0; nt < 4; ++nt) {
        f32x4 s; f32x4 d;
        float b1v = b1n[nt * 16 + (lane & 15)];
        #pragma unroll
        for (int r = 0; r < 4; ++r) { s[r] = 0.f; d[r] = b1v; }
        s = mm3(na0, PWtH[(nt * 2 + 0) * 64 + lane], PWtL[(nt * 2 + 0) * 64 + lane], s);
        s = mm3(na1, PWtH[(nt * 2 + 1) * 64 + lane], PWtL[(nt * 2 + 1) * 64 + lane], s);
        d = mm3(na0, PWbH[(nt * 2 + 0) * 64 + lane], PWbL[(nt * 2 + 0) * 64 + lane], d);
        d = mm3(na1, PWbH[(nt * 2 + 1) * 64 + lane], PWbL[(nt * 2 + 1) * 64 + lane], d);
        #pragma unroll
        for (int r = 0; r < 4; ++r) {
            int rr = rowbase + kgrp * 4 + r;
            hs[(size_t)rr * DH + nt * 16 + (lane & 15)] = s[r];
            hd[(size_t)rr * DH + nt * 16 + (lane & 15)] = d[r];
        }
    }
}

extern "C" void kernel_launch(void* const* d_in, const int* in_sizes, int n_in,
                              void* d_out, int out_size, void* d_ws, size_t ws_size,
                              hipStream_t stream) {
    const float* t      = (const float*)d_in[0];
    const int*   ei     = (const int*)d_in[1];
    const float* enc_w  = (const float*)d_in[2];
    const float* enc_b  = (const float*)d_in[3];
    const float* msg1_w = (const float*)d_in[4];
    const float* msg1_b = (const float*)d_in[5];
    const float* msg2_w = (const float*)d_in[6];
    const float* msg2_b = (const float*)d_in[7];
    const float* upd1_w = (const float*)d_in[8];
    const float* upd1_b = (const float*)d_in[9];
    const float* upd2_w = (const float*)d_in[10];
    const float* upd2_b = (const float*)d_in[11];
    const float* ro_w   = (const float*)d_in[12];
    const float* ro_b   = (const float*)d_in[13];
    float* out = (float*)d_out;

    const size_t HN2 = (size_t)TH * NN * DH;   // per-half: 2 Mi elements
    float* h      = (float*)d_ws;                   // 8 MB
    float* hs     = h + HN2;                        // 8 MB
    float* hd     = hs + HN2;                       // 8 MB
    float* aggpre = hd + HN2;                       // 8 MB
    uint4* pack   = (uint4*)(aggpre + HN2);         // 288 KB (hi + lo)
    int* counts  = (int*)(pack + 2 * LOB);
    int* offsets = counts + NN;
    int* cursor  = offsets + NN + 1;
    int* ssrc    = cursor + NN;

    hipMemsetAsync(counts, 0, NN * sizeof(int), stream);
    hist_kernel<<<EE / 256, 256, 0, stream>>>(ei, counts);
    scan_kernel<<<1, NN, 0, stream>>>(counts, offsets, cursor);
    scatter_kernel<<<EE / 256, 256, 0, stream>>>(ei, cursor, ssrc);
    prepack_kernel<<<18, 64, 0, stream>>>(msg1_w, msg2_w, upd1_w, upd2_w, pack);

    for (int half = 0; half < 2; ++half) {
        const float* th = t + half * TH;
        float* outh = out + (size_t)half * TH * NN;

        encode_mfma_kernel<<<TH * NN / 64, 256, 0, stream>>>(
            th, enc_w, enc_b, msg1_b, pack, h, hs, hd);

        for (int l = 0; l < 3; ++l) {
            agg_kernel<<<dim3(NN / 4, TH), 256, 0, stream>>>(
                hs, hd, offsets, ssrc, aggpre);
            int last = (l == 2);
            upd_mfma_kernel<<<TH * NN / 64, 256, 0, stream>>>(
                h, aggpre, counts, pack, l,
                msg2_b + (size_t)l * DH, upd1_b + (size_t)l * DH,
                upd2_b + (size_t)l * DH,
                last ? msg1_b : msg1_b + (size_t)(l + 1) * DH,
                hs, hd, ro_w, ro_b, outh, last);
        }
    }
}

// Round 5
// 346.621 us; speedup vs baseline: 19.8291x; 1.3310x over previous
//
#include <hip/hip_runtime.h>

#define TT 128
#define NN 512
#define DH 64
#define EE 8192
#define LOB (18 * 8 * 64)   // uint4 count of hi-weight fragments

typedef __bf16 bf16x8 __attribute__((ext_vector_type(8)));
typedef float f32x4 __attribute__((ext_vector_type(4)));

struct US8 { unsigned short u[8]; };
struct Frag { bf16x8 hi, lo; };

static __device__ __forceinline__ unsigned short f2bf(float x) {
    union { float f; unsigned u; } c; c.f = x;
    unsigned r = (c.u + 0x7FFFu + ((c.u >> 16) & 1u)) >> 16;   // RNE
    return (unsigned short)r;
}
static __device__ __forceinline__ float bf2f(unsigned short b) {
    union { unsigned u; float f; } c; c.u = ((unsigned)b) << 16;
    return c.f;
}
static __device__ __forceinline__ float silu_f(float x) {
    return x / (1.0f + __expf(-x));
}
static __device__ __forceinline__ Frag split8(const float* v) {
    US8 h8, l8;
    #pragma unroll
    for (int i = 0; i < 8; ++i) {
        unsigned short hu = f2bf(v[i]);
        h8.u[i] = hu;
        l8.u[i] = f2bf(v[i] - bf2f(hu));
    }
    Frag f;
    f.hi = __builtin_bit_cast(bf16x8, h8);
    f.lo = __builtin_bit_cast(bf16x8, l8);
    return f;
}
static __device__ __forceinline__ f32x4 mmac(bf16x8 a, uint4 bw, f32x4 c) {
    return __builtin_amdgcn_mfma_f32_16x16x32_bf16(
        a, __builtin_bit_cast(bf16x8, bw), c, 0, 0, 0);
}
static __device__ __forceinline__ f32x4 mm3(Frag a, uint4 wh, uint4 wl, f32x4 c) {
    c = mmac(a.hi, wh, c);
    c = mmac(a.lo, wh, c);
    c = mmac(a.hi, wl, c);
    return c;
}

// ---- fused setup: blocks 0-17 prepack weights; block 18 builds CSR ----
__global__ __launch_bounds__(512) void setup_kernel(
    const int* __restrict__ ei,
    const float* __restrict__ msg1_w, const float* __restrict__ msg2_w,
    const float* __restrict__ upd1_w, const float* __restrict__ upd2_w,
    uint4* __restrict__ pack,
    int* __restrict__ counts, int* __restrict__ offsets,
    int* __restrict__ ssrc) {
    int b = blockIdx.x;
    if (b < 18) {
        // weight prepack: hi/lo bf16 B-fragments
        int l = b / 6, bi = b % 6;
        const float* W;
        if (bi == 0)      W = msg1_w + (size_t)l * 128 * 64;
        else if (bi == 1) W = msg1_w + (size_t)l * 128 * 64 + 64 * 64;
        else if (bi == 2) W = msg2_w + (size_t)l * 64 * 64;
        else if (bi == 3) W = upd1_w + (size_t)l * 128 * 64;
        else if (bi == 4) W = upd1_w + (size_t)l * 128 * 64 + 64 * 64;
        else              W = upd2_w + (size_t)l * 64 * 64;
        int lane = threadIdx.x & 63;
        int sub  = threadIdx.x >> 6;          // 0..7 = nt*2+kc
        int nt = sub >> 1, kc = sub & 1;
        US8 oh, ol;
        #pragma unroll
        for (int i = 0; i < 8; ++i) {
            int k = kc * 32 + (lane >> 4) * 8 + i;
            int col = nt * 16 + (lane & 15);
            float w = W[k * 64 + col];
            unsigned short hu = f2bf(w);
            oh.u[i] = hu;
            ol.u[i] = f2bf(w - bf2f(hu));
        }
        size_t fi = ((size_t)b * 8 + sub) * 64 + lane;
        pack[fi]       = __builtin_bit_cast(uint4, oh);
        pack[LOB + fi] = __builtin_bit_cast(uint4, ol);
        return;
    }
    // CSR build in one block (512 threads), all in LDS
    __shared__ int cnt[NN];
    __shared__ int tmp[NN];
    __shared__ int cur[NN];
    int i = threadIdx.x;
    cnt[i] = 0;
    __syncthreads();
    #pragma unroll
    for (int r = 0; r < EE / 512; ++r)
        atomicAdd(&cnt[ei[EE + r * 512 + i]], 1);
    __syncthreads();
    int c = cnt[i];
    tmp[i] = c;
    __syncthreads();
    for (int off = 1; off < NN; off <<= 1) {
        int v = (i >= off) ? tmp[i - off] : 0;
        __syncthreads();
        tmp[i] += v;
        __syncthreads();
    }
    counts[i] = c;
    offsets[i + 1] = tmp[i];
    if (i == 0) offsets[0] = 0;
    cur[i] = tmp[i] - c;
    __syncthreads();
    #pragma unroll
    for (int r = 0; r < EE / 512; ++r) {
        int e = r * 512 + i;
        int dst = ei[EE + e];
        int pos = atomicAdd(&cur[dst], 1);
        ssrc[pos] = ei[e];
    }
}

// ---- encode + layer-0 projections (split MFMA). Wave = 16 rows. ----
__global__ __launch_bounds__(256) void encode_mfma_kernel(
    const float* __restrict__ t, const float* __restrict__ enc_w,
    const float* __restrict__ enc_b, const float* __restrict__ b1,
    const uint4* __restrict__ pack,
    float* __restrict__ h, float* __restrict__ hs, float* __restrict__ hd) {
    int lane = threadIdx.x & 63;
    int rowbase = blockIdx.x * 64 + (threadIdx.x >> 6) * 16;
    int arow = lane & 15, kgrp = lane >> 4, k0 = kgrp * 8;
    int row = rowbase + arow;
    int tt = row >> 9, n = row & (NN - 1);
    float tv = t[tt];

    float hv[16];
    #pragma unroll
    for (int kc = 0; kc < 2; ++kc) {
        #pragma unroll
        for (int i = 0; i < 8; ++i) {
            int k = kc * 32 + k0 + i;
            hv[kc * 8 + i] = tv * enc_w[k] + enc_w[(1 + n) * DH + k] + enc_b[k];
        }
        *(float4*)(h + (size_t)row * DH + kc * 32 + k0) =
            make_float4(hv[kc * 8], hv[kc * 8 + 1], hv[kc * 8 + 2], hv[kc * 8 + 3]);
        *(float4*)(h + (size_t)row * DH + kc * 32 + k0 + 4) =
            make_float4(hv[kc * 8 + 4], hv[kc * 8 + 5], hv[kc * 8 + 6], hv[kc * 8 + 7]);
    }
    Frag a0 = split8(&hv[0]), a1 = split8(&hv[8]);

    const uint4* PWtH = pack;
    const uint4* PWbH = pack + 8 * 64;
    const uint4* PWtL = PWtH + LOB;
    const uint4* PWbL = PWbH + LOB;
    #pragma unroll
    for (int nt = 0; nt < 4; ++nt) {
        f32x4 s; f32x4 d;
        float b1v = b1[nt * 16 + (lane & 15)];
        #pragma unroll
        for (int r = 0; r < 4; ++r) { s[r] = 0.f; d[r] = b1v; }
        s = mm3(a0, PWtH[(nt * 2 + 0) * 64 + lane], PWtL[(nt * 2 + 0) * 64 + lane], s);
        s = mm3(a1, PWtH[(nt * 2 + 1) * 64 + lane], PWtL[(nt * 2 + 1) * 64 + lane], s);
        d = mm3(a0, PWbH[(nt * 2 + 0) * 64 + lane], PWbL[(nt * 2 + 0) * 64 + lane], d);
        d = mm3(a1, PWbH[(nt * 2 + 1) * 64 + lane], PWbL[(nt * 2 + 1) * 64 + lane], d);
        #pragma unroll
        for (int r = 0; r < 4; ++r) {
            int rr = rowbase + kgrp * 4 + r;
            hs[(size_t)rr * DH + nt * 16 + (lane & 15)] = s[r];
            hd[(size_t)rr * DH + nt * 16 + (lane & 15)] = d[r];
        }
    }
}

// ---- edge aggregation: 4 edges in flight per wave, float4 per lane ----
// lane = eg(2b) x ch(4b); wave handles one (tt,n); 4 edges per iteration.
__global__ __launch_bounds__(256) void agg_kernel(
    const float* __restrict__ hs, const float* __restrict__ hd,
    const int* __restrict__ offsets, const int* __restrict__ ssrc,
    float* __restrict__ aggpre) {
    int lane = threadIdx.x & 63;
    int n = blockIdx.x * 4 + (threadIdx.x >> 6);
    int tt = blockIdx.y;
    size_t rowoff = ((size_t)tt * NN + n) * DH;
    int eg = lane >> 4;              // edge slot 0..3
    int ch = (lane & 15) * 4;        // channel base
    float4 hdv = *(const float4*)(hd + rowoff + ch);
    int beg = offsets[n], end = offsets[n + 1];
    const float* hst = hs + (size_t)tt * NN * DH;
    float4 acc = make_float4(0.f, 0.f, 0.f, 0.f);
    for (int base = beg; base + eg < end; base += 4) {
        int s = ssrc[base + eg];
        float4 v = *(const float4*)(hst + (size_t)s * DH + ch);
        acc.x += silu_f(v.x + hdv.x);
        acc.y += silu_f(v.y + hdv.y);
        acc.z += silu_f(v.z + hdv.z);
        acc.w += silu_f(v.w + hdv.w);
    }
    acc.x += __shfl_xor(acc.x, 16); acc.x += __shfl_xor(acc.x, 32);
    acc.y += __shfl_xor(acc.y, 16); acc.y += __shfl_xor(acc.y, 32);
    acc.z += __shfl_xor(acc.z, 16); acc.z += __shfl_xor(acc.z, 32);
    acc.w += __shfl_xor(acc.w, 16); acc.w += __shfl_xor(acc.w, 32);
    if (eg == 0) *(float4*)(aggpre + rowoff + ch) = acc;
}

// ---- fused update MLP + (next-layer projections | readout), split MFMA ----
__global__ __launch_bounds__(256) void upd_mfma_kernel(
    float* __restrict__ h, const float* __restrict__ aggpre,
    const int* __restrict__ counts, const uint4* __restrict__ pack, int l,
    const float* __restrict__ b2, const float* __restrict__ ub1,
    const float* __restrict__ ub2, const float* __restrict__ b1n,
    float* __restrict__ hs, float* __restrict__ hd,
    const float* __restrict__ ro_w, const float* __restrict__ ro_b,
    float* __restrict__ out, int last) {
    __shared__ float tileA[4][16 * 68];
    __shared__ float tileB[4][16 * 68];
    int lane = threadIdx.x & 63;
    int w = threadIdx.x >> 6;
    int rowbase = blockIdx.x * 64 + w * 16;
    float* TA = tileA[w];
    float* TB = tileB[w];
    int arow = lane & 15, kgrp = lane >> 4, k0 = kgrp * 8;
    int hrow = rowbase + arow;

    float hf[16];
    *(float4*)&hf[0]  = *(const float4*)(h + (size_t)hrow * DH + k0);
    *(float4*)&hf[4]  = *(const float4*)(h + (size_t)hrow * DH + k0 + 4);
    *(float4*)&hf[8]  = *(const float4*)(h + (size_t)hrow * DH + 32 + k0);
    *(float4*)&hf[12] = *(const float4*)(h + (size_t)hrow * DH + 32 + k0 + 4);
    Frag ha0 = split8(&hf[0]), ha1 = split8(&hf[8]);

    float gf[16];
    *(float4*)&gf[0]  = *(const float4*)(aggpre + (size_t)hrow * DH + k0);
    *(float4*)&gf[4]  = *(const float4*)(aggpre + (size_t)hrow * DH + k0 + 4);
    *(float4*)&gf[8]  = *(const float4*)(aggpre + (size_t)hrow * DH + 32 + k0);
    *(float4*)&gf[12] = *(const float4*)(aggpre + (size_t)hrow * DH + 32 + k0 + 4);
    Frag ga0 = split8(&gf[0]), ga1 = split8(&gf[8]);

    // stage 1: agg = aggpre @ W2 + deg * b2
    const uint4* PW2H = pack + (size_t)(l * 6 + 2) * 8 * 64;
    const uint4* PW2L = PW2H + LOB;
    float degv[4];
    #pragma unroll
    for (int r = 0; r < 4; ++r)
        degv[r] = (float)counts[(rowbase + kgrp * 4 + r) & (NN - 1)];
    #pragma unroll
    for (int nt = 0; nt < 4; ++nt) {
        float b2v = b2[nt * 16 + (lane & 15)];
        f32x4 a;
        #pragma unroll
        for (int r = 0; r < 4; ++r) a[r] = degv[r] * b2v;
        a = mm3(ga0, PW2H[(nt * 2 + 0) * 64 + lane], PW2L[(nt * 2 + 0) * 64 + lane], a);
        a = mm3(ga1, PW2H[(nt * 2 + 1) * 64 + lane], PW2L[(nt * 2 + 1) * 64 + lane], a);
        #pragma unroll
        for (int r = 0; r < 4; ++r)
            TA[(kgrp * 4 + r) * 68 + nt * 16 + (lane & 15)] = a[r];
    }
    float za[16];
    #pragma unroll
    for (int i = 0; i < 8; ++i) za[i] = TA[arow * 68 + k0 + i];
    #pragma unroll
    for (int i = 0; i < 8; ++i) za[8 + i] = TA[arow * 68 + 32 + k0 + i];
    Frag ka0 = split8(&za[0]), ka1 = split8(&za[8]);

    // stage 2: z = silu([h, agg] @ U1 + ub1)
    const uint4* PU1tH = pack + (size_t)(l * 6 + 3) * 8 * 64;
    const uint4* PU1bH = pack + (size_t)(l * 6 + 4) * 8 * 64;
    const uint4* PU1tL = PU1tH + LOB;
    const uint4* PU1bL = PU1bH + LOB;
    #pragma unroll
    for (int nt = 0; nt < 4; ++nt) {
        float bv = ub1[nt * 16 + (lane & 15)];
        f32x4 a;
        #pragma unroll
        for (int r = 0; r < 4; ++r) a[r] = bv;
        a = mm3(ha0, PU1tH[(nt * 2 + 0) * 64 + lane], PU1tL[(nt * 2 + 0) * 64 + lane], a);
        a = mm3(ha1, PU1tH[(nt * 2 + 1) * 64 + lane], PU1tL[(nt * 2 + 1) * 64 + lane], a);
        a = mm3(ka0, PU1bH[(nt * 2 + 0) * 64 + lane], PU1bL[(nt * 2 + 0) * 64 + lane], a);
        a = mm3(ka1, PU1bH[(nt * 2 + 1) * 64 + lane], PU1bL[(nt * 2 + 1) * 64 + lane], a);
        #pragma unroll
        for (int r = 0; r < 4; ++r)
            TB[(kgrp * 4 + r) * 68 + nt * 16 + (lane & 15)] = silu_f(a[r]);
    }
    float zb[16];
    #pragma unroll
    for (int i = 0; i < 8; ++i) zb[i] = TB[arow * 68 + k0 + i];
    #pragma unroll
    for (int i = 0; i < 8; ++i) zb[8 + i] = TB[arow * 68 + 32 + k0 + i];
    Frag kz0 = split8(&zb[0]), kz1 = split8(&zb[8]);

    // stage 3: hnew = h + z @ U2 + ub2
    const uint4* PU2H = pack + (size_t)(l * 6 + 5) * 8 * 64;
    const uint4* PU2L = PU2H + LOB;
    #pragma unroll
    for (int nt = 0; nt < 4; ++nt) {
        float bv = ub2[nt * 16 + (lane & 15)];
        f32x4 a;
        #pragma unroll
        for (int r = 0; r < 4; ++r) a[r] = bv;
        a = mm3(kz0, PU2H[(nt * 2 + 0) * 64 + lane], PU2L[(nt * 2 + 0) * 64 + lane], a);
        a = mm3(kz1, PU2H[(nt * 2 + 1) * 64 + lane], PU2L[(nt * 2 + 1) * 64 + lane], a);
        #pragma unroll
        for (int r = 0; r < 4; ++r)
            TA[(kgrp * 4 + r) * 68 + nt * 16 + (lane & 15)] = a[r];
    }
    float hn[16];
    #pragma unroll
    for (int i = 0; i < 8; ++i) hn[i] = hf[i] + TA[arow * 68 + k0 + i];
    #pragma unroll
    for (int i = 0; i < 8; ++i) hn[8 + i] = hf[8 + i] + TA[arow * 68 + 32 + k0 + i];

    if (last) {
        float v = 0.f;
        #pragma unroll
        for (int i = 0; i < 8; ++i) v += hn[i] * ro_w[k0 + i];
        #pragma unroll
        for (int i = 0; i < 8; ++i) v += hn[8 + i] * ro_w[32 + k0 + i];
        v += __shfl_xor(v, 16);
        v += __shfl_xor(v, 32);
        if (lane < 16) out[rowbase + lane] = v + ro_b[0];
        return;
    }

    *(float4*)(h + (size_t)hrow * DH + k0) = make_float4(hn[0], hn[1], hn[2], hn[3]);
    *(float4*)(h + (size_t)hrow * DH + k0 + 4) = make_float4(hn[4], hn[5], hn[6], hn[7]);
    *(float4*)(h + (size_t)hrow * DH + 32 + k0) = make_float4(hn[8], hn[9], hn[10], hn[11]);
    *(float4*)(h + (size_t)hrow * DH + 32 + k0 + 4) = make_float4(hn[12], hn[13], hn[14], hn[15]);

    Frag na0 = split8(&hn[0]), na1 = split8(&hn[8]);
    const uint4* PWtH = pack + (size_t)((l + 1) * 6 + 0) * 8 * 64;
    const uint4* PWbH = pack + (size_t)((l + 1) * 6 + 1) * 8 * 64;
    const uint4* PWtL = PWtH + LOB;
    const uint4* PWbL = PWbH + LOB;
    #pragma unroll
    for (int nt = 0; nt < 4; ++nt) {
        f32x4 s; f32x4 d;
        float b1v = b1n[nt * 16 + (lane & 15)];
        #pragma unroll
        for (int r = 0; r < 4; ++r) { s[r] = 0.f; d[r] = b1v; }
        s = mm3(na0, PWtH[(nt * 2 + 0) * 64 + lane], PWtL[(nt * 2 + 0) * 64 + lane], s);
        s = mm3(na1, PWtH[(nt * 2 + 1) * 64 + lane], PWtL[(nt * 2 + 1) * 64 + lane], s);
        d = mm3(na0, PWbH[(nt * 2 + 0) * 64 + lane], PWbL[(nt * 2 + 0) * 64 + lane], d);
        d = mm3(na1, PWbH[(nt * 2 + 1) * 64 + lane], PWbL[(nt * 2 + 1) * 64 + lane], d);
        #pragma unroll
        for (int r = 0; r < 4; ++r) {
            int rr = rowbase + kgrp * 4 + r;
            hs[(size_t)rr * DH + nt * 16 + (lane & 15)] = s[r];
            hd[(size_t)rr * DH + nt * 16 + (lane & 15)] = d[r];
        }
    }
}

extern "C" void kernel_launch(void* const* d_in, const int* in_sizes, int n_in,
                              void* d_out, int out_size, void* d_ws, size_t ws_size,
                              hipStream_t stream) {
    const float* t      = (const float*)d_in[0];
    const int*   ei     = (const int*)d_in[1];
    const float* enc_w  = (const float*)d_in[2];
    const float* enc_b  = (const float*)d_in[3];
    const float* msg1_w = (const float*)d_in[4];
    const float* msg1_b = (const float*)d_in[5];
    const float* msg2_w = (const float*)d_in[6];
    const float* msg2_b = (const float*)d_in[7];
    const float* upd1_w = (const float*)d_in[8];
    const float* upd1_b = (const float*)d_in[9];
    const float* upd2_w = (const float*)d_in[10];
    const float* upd2_b = (const float*)d_in[11];
    const float* ro_w   = (const float*)d_in[12];
    const float* ro_b   = (const float*)d_in[13];
    float* out = (float*)d_out;

    const size_t HN = (size_t)TT * NN * DH;   // 4 Mi elements
    float* h      = (float*)d_ws;                   // 16 MB
    float* hs     = h + HN;                         // 16 MB
    float* hd     = hs + HN;                        // 16 MB
    float* aggpre = hd + HN;                        // 16 MB
    uint4* pack   = (uint4*)(aggpre + HN);          // 288 KB (hi+lo)
    int* counts  = (int*)(pack + 2 * LOB);
    int* offsets = counts + NN;
    int* ssrc    = offsets + NN + 1;

    setup_kernel<<<19, 512, 0, stream>>>(ei, msg1_w, msg2_w, upd1_w, upd2_w,
                                         pack, counts, offsets, ssrc);

    encode_mfma_kernel<<<TT * NN / 64, 256, 0, stream>>>(
        t, enc_w, enc_b, msg1_b, pack, h, hs, hd);

    for (int l = 0; l < 3; ++l) {
        agg_kernel<<<dim3(NN / 4, TT), 256, 0, stream>>>(
            hs, hd, offsets, ssrc, aggpre);
        int last = (l == 2);
        upd_mfma_kernel<<<TT * NN / 64, 256, 0, stream>>>(
            h, aggpre, counts, pack, l,
            msg2_b + (size_t)l * DH, upd1_b + (size_t)l * DH,
            upd2_b + (size_t)l * DH,
            last ? msg1_b : msg1_b + (size_t)(l + 1) * DH,
            hs, hd, ro_w, ro_b, out, last);
    }
}

// Round 6
// 298.612 us; speedup vs baseline: 23.0171x; 1.1608x over previous
//
#include <hip/hip_runtime.h>

#define TT 128
#define NN 512
#define DH 64
#define EE 8192
#define LOB (18 * 8 * 64)   // uint4 count of hi-weight fragments

typedef __bf16 bf16x8 __attribute__((ext_vector_type(8)));
typedef float f32x4 __attribute__((ext_vector_type(4)));

struct US8 { unsigned short u[8]; };
struct Frag { bf16x8 hi, lo; };

static __device__ __forceinline__ unsigned short f2bf(float x) {
    union { float f; unsigned u; } c; c.f = x;
    unsigned r = (c.u + 0x7FFFu + ((c.u >> 16) & 1u)) >> 16;   // RNE
    return (unsigned short)r;
}
static __device__ __forceinline__ float bf2f(unsigned short b) {
    union { unsigned u; float f; } c; c.u = ((unsigned)b) << 16;
    return c.f;
}
// fast silu accumulate: acc + x * rcp(1 + exp(-x))
static __device__ __forceinline__ float silu_acc(float a, float b, float acc) {
    float x = a + b;
    float e = __expf(-x);
    return fmaf(x, __builtin_amdgcn_rcpf(1.0f + e), acc);
}
static __device__ __forceinline__ float silu_f(float x) {
    float e = __expf(-x);
    return x * __builtin_amdgcn_rcpf(1.0f + e);
}
// split fp32 -> hi/lo bf16 via native casts (compiler emits v_cvt_pk_bf16_f32)
static __device__ __forceinline__ Frag split8(const float* v) {
    Frag f;
    #pragma unroll
    for (int i = 0; i < 8; ++i) {
        __bf16 hb = (__bf16)v[i];
        f.hi[i] = hb;
        f.lo[i] = (__bf16)(v[i] - (float)hb);
    }
    return f;
}
static __device__ __forceinline__ f32x4 mmac(bf16x8 a, uint4 bw, f32x4 c) {
    return __builtin_amdgcn_mfma_f32_16x16x32_bf16(
        a, __builtin_bit_cast(bf16x8, bw), c, 0, 0, 0);
}
static __device__ __forceinline__ f32x4 mm3(Frag a, uint4 wh, uint4 wl, f32x4 c) {
    c = mmac(a.hi, wh, c);
    c = mmac(a.lo, wh, c);
    c = mmac(a.hi, wl, c);
    return c;
}

// ---- fused setup: blocks 0-17 prepack weights; block 18 builds CSR ----
__global__ __launch_bounds__(512) void setup_kernel(
    const int* __restrict__ ei,
    const float* __restrict__ msg1_w, const float* __restrict__ msg2_w,
    const float* __restrict__ upd1_w, const float* __restrict__ upd2_w,
    uint4* __restrict__ pack,
    int* __restrict__ counts, int* __restrict__ offsets,
    int* __restrict__ ssrc) {
    int b = blockIdx.x;
    if (b < 18) {
        int l = b / 6, bi = b % 6;
        const float* W;
        if (bi == 0)      W = msg1_w + (size_t)l * 128 * 64;
        else if (bi == 1) W = msg1_w + (size_t)l * 128 * 64 + 64 * 64;
        else if (bi == 2) W = msg2_w + (size_t)l * 64 * 64;
        else if (bi == 3) W = upd1_w + (size_t)l * 128 * 64;
        else if (bi == 4) W = upd1_w + (size_t)l * 128 * 64 + 64 * 64;
        else              W = upd2_w + (size_t)l * 64 * 64;
        int lane = threadIdx.x & 63;
        int sub  = threadIdx.x >> 6;          // 0..7 = nt*2+kc
        int nt = sub >> 1, kc = sub & 1;
        US8 oh, ol;
        #pragma unroll
        for (int i = 0; i < 8; ++i) {
            int k = kc * 32 + (lane >> 4) * 8 + i;
            int col = nt * 16 + (lane & 15);
            float w = W[k * 64 + col];
            unsigned short hu = f2bf(w);
            oh.u[i] = hu;
            ol.u[i] = f2bf(w - bf2f(hu));
        }
        size_t fi = ((size_t)b * 8 + sub) * 64 + lane;
        pack[fi]       = __builtin_bit_cast(uint4, oh);
        pack[LOB + fi] = __builtin_bit_cast(uint4, ol);
        return;
    }
    // CSR build in one block, all in LDS
    __shared__ int cnt[NN];
    __shared__ int tmp[NN];
    __shared__ int cur[NN];
    int i = threadIdx.x;
    cnt[i] = 0;
    __syncthreads();
    #pragma unroll
    for (int r = 0; r < EE / 512; ++r)
        atomicAdd(&cnt[ei[EE + r * 512 + i]], 1);
    __syncthreads();
    int c = cnt[i];
    tmp[i] = c;
    __syncthreads();
    for (int off = 1; off < NN; off <<= 1) {
        int v = (i >= off) ? tmp[i - off] : 0;
        __syncthreads();
        tmp[i] += v;
        __syncthreads();
    }
    counts[i] = c;
    offsets[i + 1] = tmp[i];
    if (i == 0) offsets[0] = 0;
    cur[i] = tmp[i] - c;
    __syncthreads();
    #pragma unroll
    for (int r = 0; r < EE / 512; ++r) {
        int e = r * 512 + i;
        int dst = ei[EE + e];
        int pos = atomicAdd(&cur[dst], 1);
        ssrc[pos] = ei[e];
    }
}

// ---- encode + layer-0 projections (split MFMA). Wave = 16 rows. ----
__global__ __launch_bounds__(256) void encode_mfma_kernel(
    const float* __restrict__ t, const float* __restrict__ enc_w,
    const float* __restrict__ enc_b, const float* __restrict__ b1,
    const uint4* __restrict__ pack,
    float* __restrict__ h, float* __restrict__ hs, float* __restrict__ hd) {
    int lane = threadIdx.x & 63;
    int rowbase = blockIdx.x * 64 + (threadIdx.x >> 6) * 16;
    int arow = lane & 15, kgrp = lane >> 4, k0 = kgrp * 8;
    int row = rowbase + arow;
    int tt = row >> 9, n = row & (NN - 1);
    float tv = t[tt];

    float hv[16];
    #pragma unroll
    for (int kc = 0; kc < 2; ++kc) {
        #pragma unroll
        for (int i = 0; i < 8; ++i) {
            int k = kc * 32 + k0 + i;
            hv[kc * 8 + i] = tv * enc_w[k] + enc_w[(1 + n) * DH + k] + enc_b[k];
        }
        *(float4*)(h + (size_t)row * DH + kc * 32 + k0) =
            make_float4(hv[kc * 8], hv[kc * 8 + 1], hv[kc * 8 + 2], hv[kc * 8 + 3]);
        *(float4*)(h + (size_t)row * DH + kc * 32 + k0 + 4) =
            make_float4(hv[kc * 8 + 4], hv[kc * 8 + 5], hv[kc * 8 + 6], hv[kc * 8 + 7]);
    }
    Frag a0 = split8(&hv[0]), a1 = split8(&hv[8]);

    const uint4* PWtH = pack;
    const uint4* PWbH = pack + 8 * 64;
    const uint4* PWtL = PWtH + LOB;
    const uint4* PWbL = PWbH + LOB;
    #pragma unroll
    for (int nt = 0; nt < 4; ++nt) {
        f32x4 s; f32x4 d;
        float b1v = b1[nt * 16 + (lane & 15)];
        #pragma unroll
        for (int r = 0; r < 4; ++r) { s[r] = 0.f; d[r] = b1v; }
        s = mm3(a0, PWtH[(nt * 2 + 0) * 64 + lane], PWtL[(nt * 2 + 0) * 64 + lane], s);
        s = mm3(a1, PWtH[(nt * 2 + 1) * 64 + lane], PWtL[(nt * 2 + 1) * 64 + lane], s);
        d = mm3(a0, PWbH[(nt * 2 + 0) * 64 + lane], PWbL[(nt * 2 + 0) * 64 + lane], d);
        d = mm3(a1, PWbH[(nt * 2 + 1) * 64 + lane], PWbL[(nt * 2 + 1) * 64 + lane], d);
        #pragma unroll
        for (int r = 0; r < 4; ++r) {
            int rr = rowbase + kgrp * 4 + r;
            hs[(size_t)rr * DH + nt * 16 + (lane & 15)] = s[r];
            hd[(size_t)rr * DH + nt * 16 + (lane & 15)] = d[r];
        }
    }
}

// ---- edge aggregation: 8 edges in flight per wave (2 chains x 4 slots) ----
__global__ __launch_bounds__(256) void agg_kernel(
    const float* __restrict__ hs, const float* __restrict__ hd,
    const int* __restrict__ offsets, const int* __restrict__ ssrc,
    float* __restrict__ aggpre) {
    int lane = threadIdx.x & 63;
    int n = blockIdx.x * 4 + (threadIdx.x >> 6);
    int tt = blockIdx.y;
    size_t rowoff = ((size_t)tt * NN + n) * DH;
    int eg = lane >> 4;                 // edge slot 0..3
    int ch4 = (lane & 15) * 16;         // byte offset of this lane's float4
    float4 hdv = *(const float4*)(hd + rowoff + (lane & 15) * 4);
    int beg = offsets[n], end = offsets[n + 1];
    const char* hb = (const char*)(hs + (size_t)tt * NN * DH);
    float4 acc = make_float4(0.f, 0.f, 0.f, 0.f);
    int i = beg + eg;
    for (; i + 4 < end; i += 8) {
        int s0 = ssrc[i] << 8;
        int s1 = ssrc[i + 4] << 8;
        float4 v0 = *(const float4*)(hb + s0 + ch4);
        float4 v1 = *(const float4*)(hb + s1 + ch4);
        acc.x = silu_acc(v0.x, hdv.x, acc.x);
        acc.y = silu_acc(v0.y, hdv.y, acc.y);
        acc.z = silu_acc(v0.z, hdv.z, acc.z);
        acc.w = silu_acc(v0.w, hdv.w, acc.w);
        acc.x = silu_acc(v1.x, hdv.x, acc.x);
        acc.y = silu_acc(v1.y, hdv.y, acc.y);
        acc.z = silu_acc(v1.z, hdv.z, acc.z);
        acc.w = silu_acc(v1.w, hdv.w, acc.w);
    }
    if (i < end) {
        int s0 = ssrc[i] << 8;
        float4 v0 = *(const float4*)(hb + s0 + ch4);
        acc.x = silu_acc(v0.x, hdv.x, acc.x);
        acc.y = silu_acc(v0.y, hdv.y, acc.y);
        acc.z = silu_acc(v0.z, hdv.z, acc.z);
        acc.w = silu_acc(v0.w, hdv.w, acc.w);
    }
    acc.x += __shfl_xor(acc.x, 16); acc.x += __shfl_xor(acc.x, 32);
    acc.y += __shfl_xor(acc.y, 16); acc.y += __shfl_xor(acc.y, 32);
    acc.z += __shfl_xor(acc.z, 16); acc.z += __shfl_xor(acc.z, 32);
    acc.w += __shfl_xor(acc.w, 16); acc.w += __shfl_xor(acc.w, 32);
    if (eg == 0) *(float4*)(aggpre + rowoff + (lane & 15) * 4) = acc;
}

// ---- fused update MLP + (next-layer projections | readout), split MFMA ----
__global__ __launch_bounds__(256) void upd_mfma_kernel(
    float* __restrict__ h, const float* __restrict__ aggpre,
    const int* __restrict__ counts, const uint4* __restrict__ pack, int l,
    const float* __restrict__ b2, const float* __restrict__ ub1,
    const float* __restrict__ ub2, const float* __restrict__ b1n,
    float* __restrict__ hs, float* __restrict__ hd,
    const float* __restrict__ ro_w, const float* __restrict__ ro_b,
    float* __restrict__ out, int last) {
    __shared__ float tileA[4][16 * 68];
    __shared__ float tileB[4][16 * 68];
    int lane = threadIdx.x & 63;
    int w = threadIdx.x >> 6;
    int rowbase = blockIdx.x * 64 + w * 16;
    float* TA = tileA[w];
    float* TB = tileB[w];
    int arow = lane & 15, kgrp = lane >> 4, k0 = kgrp * 8;
    int hrow = rowbase + arow;

    float hf[16];
    *(float4*)&hf[0]  = *(const float4*)(h + (size_t)hrow * DH + k0);
    *(float4*)&hf[4]  = *(const float4*)(h + (size_t)hrow * DH + k0 + 4);
    *(float4*)&hf[8]  = *(const float4*)(h + (size_t)hrow * DH + 32 + k0);
    *(float4*)&hf[12] = *(const float4*)(h + (size_t)hrow * DH + 32 + k0 + 4);
    Frag ha0 = split8(&hf[0]), ha1 = split8(&hf[8]);

    float gf[16];
    *(float4*)&gf[0]  = *(const float4*)(aggpre + (size_t)hrow * DH + k0);
    *(float4*)&gf[4]  = *(const float4*)(aggpre + (size_t)hrow * DH + k0 + 4);
    *(float4*)&gf[8]  = *(const float4*)(aggpre + (size_t)hrow * DH + 32 + k0);
    *(float4*)&gf[12] = *(const float4*)(aggpre + (size_t)hrow * DH + 32 + k0 + 4);
    Frag ga0 = split8(&gf[0]), ga1 = split8(&gf[8]);

    // stage 1: agg = aggpre @ W2 + deg * b2
    const uint4* PW2H = pack + (size_t)(l * 6 + 2) * 8 * 64;
    const uint4* PW2L = PW2H + LOB;
    float degv[4];
    #pragma unroll
    for (int r = 0; r < 4; ++r)
        degv[r] = (float)counts[(rowbase + kgrp * 4 + r) & (NN - 1)];
    #pragma unroll
    for (int nt = 0; nt < 4; ++nt) {
        float b2v = b2[nt * 16 + (lane & 15)];
        f32x4 a;
        #pragma unroll
        for (int r = 0; r < 4; ++r) a[r] = degv[r] * b2v;
        a = mm3(ga0, PW2H[(nt * 2 + 0) * 64 + lane], PW2L[(nt * 2 + 0) * 64 + lane], a);
        a = mm3(ga1, PW2H[(nt * 2 + 1) * 64 + lane], PW2L[(nt * 2 + 1) * 64 + lane], a);
        #pragma unroll
        for (int r = 0; r < 4; ++r)
            TA[(kgrp * 4 + r) * 68 + nt * 16 + (lane & 15)] = a[r];
    }
    float za[16];
    #pragma unroll
    for (int i = 0; i < 8; ++i) za[i] = TA[arow * 68 + k0 + i];
    #pragma unroll
    for (int i = 0; i < 8; ++i) za[8 + i] = TA[arow * 68 + 32 + k0 + i];
    Frag ka0 = split8(&za[0]), ka1 = split8(&za[8]);

    // stage 2: z = silu([h, agg] @ U1 + ub1)
    const uint4* PU1tH = pack + (size_t)(l * 6 + 3) * 8 * 64;
    const uint4* PU1bH = pack + (size_t)(l * 6 + 4) * 8 * 64;
    const uint4* PU1tL = PU1tH + LOB;
    const uint4* PU1bL = PU1bH + LOB;
    #pragma unroll
    for (int nt = 0; nt < 4; ++nt) {
        float bv = ub1[nt * 16 + (lane & 15)];
        f32x4 a;
        #pragma unroll
        for (int r = 0; r < 4; ++r) a[r] = bv;
        a = mm3(ha0, PU1tH[(nt * 2 + 0) * 64 + lane], PU1tL[(nt * 2 + 0) * 64 + lane], a);
        a = mm3(ha1, PU1tH[(nt * 2 + 1) * 64 + lane], PU1tL[(nt * 2 + 1) * 64 + lane], a);
        a = mm3(ka0, PU1bH[(nt * 2 + 0) * 64 + lane], PU1bL[(nt * 2 + 0) * 64 + lane], a);
        a = mm3(ka1, PU1bH[(nt * 2 + 1) * 64 + lane], PU1bL[(nt * 2 + 1) * 64 + lane], a);
        #pragma unroll
        for (int r = 0; r < 4; ++r)
            TB[(kgrp * 4 + r) * 68 + nt * 16 + (lane & 15)] = silu_f(a[r]);
    }
    float zb[16];
    #pragma unroll
    for (int i = 0; i < 8; ++i) zb[i] = TB[arow * 68 + k0 + i];
    #pragma unroll
    for (int i = 0; i < 8; ++i) zb[8 + i] = TB[arow * 68 + 32 + k0 + i];
    Frag kz0 = split8(&zb[0]), kz1 = split8(&zb[8]);

    // stage 3: hnew = h + z @ U2 + ub2
    const uint4* PU2H = pack + (size_t)(l * 6 + 5) * 8 * 64;
    const uint4* PU2L = PU2H + LOB;
    #pragma unroll
    for (int nt = 0; nt < 4; ++nt) {
        float bv = ub2[nt * 16 + (lane & 15)];
        f32x4 a;
        #pragma unroll
        for (int r = 0; r < 4; ++r) a[r] = bv;
        a = mm3(kz0, PU2H[(nt * 2 + 0) * 64 + lane], PU2L[(nt * 2 + 0) * 64 + lane], a);
        a = mm3(kz1, PU2H[(nt * 2 + 1) * 64 + lane], PU2L[(nt * 2 + 1) * 64 + lane], a);
        #pragma unroll
        for (int r = 0; r < 4; ++r)
            TA[(kgrp * 4 + r) * 68 + nt * 16 + (lane & 15)] = a[r];
    }
    float hn[16];
    #pragma unroll
    for (int i = 0; i < 8; ++i) hn[i] = hf[i] + TA[arow * 68 + k0 + i];
    #pragma unroll
    for (int i = 0; i < 8; ++i) hn[8 + i] = hf[8 + i] + TA[arow * 68 + 32 + k0 + i];

    if (last) {
        float v = 0.f;
        #pragma unroll
        for (int i = 0; i < 8; ++i) v += hn[i] * ro_w[k0 + i];
        #pragma unroll
        for (int i = 0; i < 8; ++i) v += hn[8 + i] * ro_w[32 + k0 + i];
        v += __shfl_xor(v, 16);
        v += __shfl_xor(v, 32);
        if (lane < 16) out[rowbase + lane] = v + ro_b[0];
        return;
    }

    *(float4*)(h + (size_t)hrow * DH + k0) = make_float4(hn[0], hn[1], hn[2], hn[3]);
    *(float4*)(h + (size_t)hrow * DH + k0 + 4) = make_float4(hn[4], hn[5], hn[6], hn[7]);
    *(float4*)(h + (size_t)hrow * DH + 32 + k0) = make_float4(hn[8], hn[9], hn[10], hn[11]);
    *(float4*)(h + (size_t)hrow * DH + 32 + k0 + 4) = make_float4(hn[12], hn[13], hn[14], hn[15]);

    Frag na0 = split8(&hn[0]), na1 = split8(&hn[8]);
    const uint4* PWtH = pack + (size_t)((l + 1) * 6 + 0) * 8 * 64;
    const uint4* PWbH = pack + (size_t)((l + 1) * 6 + 1) * 8 * 64;
    const uint4* PWtL = PWtH + LOB;
    const uint4* PWbL = PWbH + LOB;
    #pragma unroll
    for (int nt = 0; nt < 4; ++nt) {
        f32x4 s; f32x4 d;
        float b1v = b1n[nt * 16 + (lane & 15)];
        #pragma unroll
        for (int r = 0; r < 4; ++r) { s[r] = 0.f; d[r] = b1v; }
        s = mm3(na0, PWtH[(nt * 2 + 0) * 64 + lane], PWtL[(nt * 2 + 0) * 64 + lane], s);
        s = mm3(na1, PWtH[(nt * 2 + 1) * 64 + lane], PWtL[(nt * 2 + 1) * 64 + lane], s);
        d = mm3(na0, PWbH[(nt * 2 + 0) * 64 + lane], PWbL[(nt * 2 + 0) * 64 + lane], d);
        d = mm3(na1, PWbH[(nt * 2 + 1) * 64 + lane], PWbL[(nt * 2 + 1) * 64 + lane], d);
        #pragma unroll
        for (int r = 0; r < 4; ++r) {
            int rr = rowbase + kgrp * 4 + r;
            hs[(size_t)rr * DH + nt * 16 + (lane & 15)] = s[r];
            hd[(size_t)rr * DH + nt * 16 + (lane & 15)] = d[r];
        }
    }
}

extern "C" void kernel_launch(void* const* d_in, const int* in_sizes, int n_in,
                              void* d_out, int out_size, void* d_ws, size_t ws_size,
                              hipStream_t stream) {
    const float* t      = (const float*)d_in[0];
    const int*   ei     = (const int*)d_in[1];
    const float* enc_w  = (const float*)d_in[2];
    const float* enc_b  = (const float*)d_in[3];
    const float* msg1_w = (const float*)d_in[4];
    const float* msg1_b = (const float*)d_in[5];
    const float* msg2_w = (const float*)d_in[6];
    const float* msg2_b = (const float*)d_in[7];
    const float* upd1_w = (const float*)d_in[8];
    const float* upd1_b = (const float*)d_in[9];
    const float* upd2_w = (const float*)d_in[10];
    const float* upd2_b = (const float*)d_in[11];
    const float* ro_w   = (const float*)d_in[12];
    const float* ro_b   = (const float*)d_in[13];
    float* out = (float*)d_out;

    const size_t HN = (size_t)TT * NN * DH;   // 4 Mi elements
    float* h      = (float*)d_ws;                   // 16 MB
    float* hs     = h + HN;                         // 16 MB
    float* hd     = hs + HN;                        // 16 MB
    float* aggpre = hd + HN;                        // 16 MB
    uint4* pack   = (uint4*)(aggpre + HN);          // 288 KB (hi+lo)
    int* counts  = (int*)(pack + 2 * LOB);
    int* offsets = counts + NN;
    int* ssrc    = offsets + NN + 1;

    setup_kernel<<<19, 512, 0, stream>>>(ei, msg1_w, msg2_w, upd1_w, upd2_w,
                                         pack, counts, offsets, ssrc);

    encode_mfma_kernel<<<TT * NN / 64, 256, 0, stream>>>(
        t, enc_w, enc_b, msg1_b, pack, h, hs, hd);

    for (int l = 0; l < 3; ++l) {
        agg_kernel<<<dim3(NN / 4, TT), 256, 0, stream>>>(
            hs, hd, offsets, ssrc, aggpre);
        int last = (l == 2);
        upd_mfma_kernel<<<TT * NN / 64, 256, 0, stream>>>(
            h, aggpre, counts, pack, l,
            msg2_b + (size_t)l * DH, upd1_b + (size_t)l * DH,
            upd2_b + (size_t)l * DH,
            last ? msg1_b : msg1_b + (size_t)(l + 1) * DH,
            hs, hd, ro_w, ro_b, out, last);
    }
}